// Round 11
// baseline (353.963 us; speedup 1.0000x reference)
//
#include <hip/hip_runtime.h>

// Round 11: K in REGISTERS (direct L2->VGPR fragment loads from tiled layout,
// ping-pong prefetch), V in LDS (double-buffered, linear gl16 staging).
// Cuts LDS traffic/CU 17MB -> ~7.5MB. R8 barrier cadence, KVBLK=32 softmax,
// exp2 domain. launch_bounds(512,1): ~300 VGPR legal, LDS pins 1 block/CU.
//   d_in: 0=x f32, 1=mask i32, 2=Wk, 3=Wq, 4=Wv
// ws (f16): qT [BT/32][8192] | kT [BT/16][4096] | vT [BT/16][4096]
//   qT: [(qh*8+kc)*512 + l4*128 + tok*8 + j]  (x log2e/16 folded)
//   kT: [kc*512 + ch*128 + key*8 + j]   <-> K[16t+key][kc*32+ch*8+j]
//   vT: [dt*512 + kh*256 + d31*8 + j]   <-> V^T[dt*32+d31][16t+kh*8+j]

typedef __attribute__((ext_vector_type(8)))  _Float16 f16x8;
typedef __attribute__((ext_vector_type(4)))  _Float16 f16x4;
typedef __attribute__((ext_vector_type(4)))  float    f32x4;
typedef __attribute__((ext_vector_type(16))) float    f32x16;

constexpr int Bb = 4;
constexpr int Tt = 4096;
constexpr int Cc = 256;
constexpr int BT = Bb * Tt;
constexpr int NT2 = 32;                // 32-key super-tiles per warp (32x32 = 1024 keys)

#define MFMA16(a, b, c) __builtin_amdgcn_mfma_f32_16x16x32_f16((a), (b), (c), 0, 0, 0)
#define MFMA32(a, b, c) __builtin_amdgcn_mfma_f32_32x32x16_f16((a), (b), (c), 0, 0, 0)

__device__ __forceinline__ void gl16(const _Float16* gp, char* lp) {
    __builtin_amdgcn_global_load_lds(
        (const __attribute__((address_space(1))) void*)gp,
        (__attribute__((address_space(3))) void*)lp, 16, 0, 0);
}

// ---------------- Kernel A: fused QKV projection (verbatim round 10) ---------
__global__ __launch_bounds__(256) void qkv_proj(
    const float* __restrict__ x,
    const float* __restrict__ Wq, const float* __restrict__ Wk,
    const float* __restrict__ Wv,
    _Float16* __restrict__ qo, _Float16* __restrict__ ko,
    _Float16* __restrict__ vto)
{
    extern __shared__ _Float16 sm[];
    _Float16* xs = sm;              // [128][264]
    _Float16* wsm = sm + 128 * 264; // [128][264]

    const int tid = threadIdx.x;
    const int m0  = blockIdx.x * 128;
    const int ny  = blockIdx.y;
    const int mat = ny >> 1;              // 0=q 1=k 2=v
    const int d0  = (ny & 1) * 128;
    const float* W = (mat == 0) ? Wq : (mat == 1 ? Wk : Wv);

#pragma unroll
    for (int i = 0; i < 32; ++i) {
        int flat = i * 256 + tid;
        int r = flat >> 6, c4 = (flat & 63) << 2;
        float4 v = *reinterpret_cast<const float4*>(x + (size_t)(m0 + r) * Cc + c4);
        f16x4 h = { (_Float16)v.x, (_Float16)v.y, (_Float16)v.z, (_Float16)v.w };
        *reinterpret_cast<f16x4*>(xs + r * 264 + c4) = h;
    }
#pragma unroll
    for (int i = 0; i < 32; ++i) {
        int flat = i * 256 + tid;
        int r = flat >> 6, c4 = (flat & 63) << 2;
        float4 v = *reinterpret_cast<const float4*>(W + (size_t)(d0 + r) * Cc + c4);
        f16x4 h = { (_Float16)v.x, (_Float16)v.y, (_Float16)v.z, (_Float16)v.w };
        *reinterpret_cast<f16x4*>(wsm + r * 264 + c4) = h;
    }
    __syncthreads();

    const int w = tid >> 6, lane = tid & 63;
    const int lr = lane & 15, lg = lane >> 4;

    f32x4 acc[2][8] = {};

#pragma unroll
    for (int kc = 0; kc < 8; ++kc) {
        const int c0 = kc * 32 + lg * 8;
        f16x8 xf[2], wf[8];
#pragma unroll
        for (int mb = 0; mb < 2; ++mb)
            xf[mb] = *reinterpret_cast<const f16x8*>(xs + (w * 32 + mb * 16 + lr) * 264 + c0);
#pragma unroll
        for (int db = 0; db < 8; ++db)
            wf[db] = *reinterpret_cast<const f16x8*>(wsm + (db * 16 + lr) * 264 + c0);
        if (mat != 2) {
#pragma unroll
            for (int mb = 0; mb < 2; ++mb)
#pragma unroll
                for (int db = 0; db < 8; ++db)
                    acc[mb][db] = MFMA16(wf[db], xf[mb], acc[mb][db]);   // D[d][tok]
        } else {
#pragma unroll
            for (int mb = 0; mb < 2; ++mb)
#pragma unroll
                for (int db = 0; db < 8; ++db)
                    acc[mb][db] = MFMA16(xf[mb], wf[db], acc[mb][db]);   // D[tok][d]
        }
    }

    if (mat != 2) {
        // q scale: 1/sqrt(256) * log2(e)  (softmax runs in base-2 domain)
        const float sc = (mat == 0) ? 0.0625f * 1.44269504f : 1.0f;
        const int jj  = (lg & 1) * 4;
#pragma unroll
        for (int mb = 0; mb < 2; ++mb)
#pragma unroll
            for (int db = 0; db < 8; ++db) {
                int m  = m0 + w * 32 + mb * 16 + lr;
                int c  = d0 + db * 16 + lg * 4;
                int kc = c >> 5;
                int ch = (c >> 3) & 3;
                f32x4 a = acc[mb][db];
                f16x4 h = { (_Float16)(a.x * sc), (_Float16)(a.y * sc),
                            (_Float16)(a.z * sc), (_Float16)(a.w * sc) };
                if (mat == 0) {
                    size_t off = (size_t)(m >> 5) * 8192 + (((m >> 4) & 1) * 8 + kc) * 512
                               + ch * 128 + (m & 15) * 8 + jj;
                    *reinterpret_cast<f16x4*>(qo + off) = h;
                } else {
                    size_t off = (size_t)(m >> 4) * 4096 + kc * 512
                               + ch * 128 + (m & 15) * 8 + jj;
                    *reinterpret_cast<f16x4*>(ko + off) = h;
                }
            }
    } else {
        const int jj = (lg & 1) * 4;
        const int kh = (lg >> 1) & 1;
#pragma unroll
        for (int mb = 0; mb < 2; ++mb)
#pragma unroll
            for (int db = 0; db < 8; ++db) {
                int d = d0 + db * 16 + lr;
                int m = m0 + w * 32 + mb * 16 + lg * 4;
                f32x4 a = acc[mb][db];
                f16x4 h = { (_Float16)a.x, (_Float16)a.y, (_Float16)a.z, (_Float16)a.w };
                size_t off = (size_t)(m >> 4) * 4096 + (d >> 5) * 512
                           + kh * 256 + (d & 31) * 8 + jj;
                *reinterpret_cast<f16x4*>(vto + off) = h;
            }
    }
}

// ---------------- Kernel B: flash attention, K-in-registers ----------------
// LDS map (bytes): [0,131072)      V: 4 g x 2 dbuf x [2 sub x 8KB]
//                  [131072,151552) per-warp P [8][32][40] f16
//                  [151552,152576) mex f32[2][4][32]; [152576,153600) lex
// epilogue reuses [0,132096) as oex f32[4][32][258]
__global__ __launch_bounds__(512, 1) void attn_kernel(
    const _Float16* __restrict__ qb, const _Float16* __restrict__ kb,
    const _Float16* __restrict__ vtb, const int* __restrict__ mask,
    float* __restrict__ outp)
{
    extern __shared__ char smraw[];
    float* mex32 = (float*)(smraw + 151552);
    float* lex32 = (float*)(smraw + 152576);
    float* oexf  = (float*)smraw;

    const int tid = threadIdx.x, w = tid >> 6, lane = tid & 63;
    const int qw = w >> 2, g = w & 3;
    const int l15 = lane & 15, l4 = lane >> 4;
    const int l31 = lane & 31, l5 = lane >> 5;

    const int bid = blockIdx.x;
    const int b   = (bid & 7) >> 1;                    // batch -> XCD pair
    const int qt  = ((bid >> 3) << 1) | (bid & 1);     // [0,64)
    const int q0  = qt * 64;
    const size_t base = (size_t)b * Tt * Cc;
    const int* maskb = mask + (size_t)b * Tt;
    const _Float16* kTb = kb + base;
    const _Float16* vTb = vtb + base;

    // Q fragments: Q[q0 + qw*32 + qh*16 + l15][kc*32 + l4*8 + j]
    f16x8 qf[2][8];
    {
        const _Float16* qTb = qb + (size_t)(b * 128 + qt * 2 + qw) * 8192;
#pragma unroll
        for (int qh = 0; qh < 2; ++qh)
#pragma unroll
            for (int kc = 0; kc < 8; ++kc)
                qf[qh][kc] = *reinterpret_cast<const f16x8*>(
                    qTb + (qh * 8 + kc) * 512 + l4 * 128 + l15 * 8);
    }

    _Float16* pw = (_Float16*)(smraw + 131072) + w * 1280;   // [32][40]

    f32x16 o[8] = {};                  // O^T[d = dt*32+(r&3)+8*(r>>2)+4*l5][q=l31]
    float m0r = -60.f, m1r = -60.f, l0r = 0.f, l1r = 0.f;

    // K fragment loads: straight from fragment-tiled global (L2-resident)
    f16x8 ka[8], kb2[8];
    auto LOADK = [&](f16x8 (&kr)[8], int tile) {
        const _Float16* src = kTb + (size_t)tile * 4096 + l4 * 128 + l15 * 8;
#pragma unroll
        for (int kc = 0; kc < 8; ++kc)
            kr[kc] = *reinterpret_cast<const f16x8*>(src + kc * 512);
    };
    // V staging: warp (qw,g) stages 16-key sub-tile `qw` of super-tile t
    auto STAGE_V = [&](int t) {
        char* dst = smraw + g * 32768 + (t & 1) * 16384 + qw * 8192;
        const _Float16* src = vTb + (size_t)(g * 64 + 2 * t + qw) * 4096 + lane * 8;
#pragma unroll
        for (int j = 0; j < 8; ++j) gl16(src + j * 512, dst + j * 1024);
    };

    // prologue
    STAGE_V(0);
    LOADK(ka,  g * 64 + 0);
    LOADK(kb2, g * 64 + 1);
    int4 mc0 = *reinterpret_cast<const int4*>(maskb + g * 1024 + l4 * 4);
    int4 mc1 = *reinterpret_cast<const int4*>(maskb + g * 1024 + 16 + l4 * 4);

#pragma unroll 1
    for (int t = 0; t < NT2; ++t) {
        __syncthreads();               // drains vm+lgkm; V(t) ready in dbuf[t&1]
        if (t + 1 < NT2) STAGE_V(t + 1);

        // QK sub0: S^T[key = l4*4 + r][q = qh*16 + l15]
        f32x4 s00 = { 0.f, 0.f, 0.f, 0.f }, s01 = { 0.f, 0.f, 0.f, 0.f };
        __builtin_amdgcn_s_setprio(1);
#pragma unroll
        for (int kc = 0; kc < 8; ++kc) {
            s00 = MFMA16(ka[kc], qf[0][kc], s00);
            s01 = MFMA16(ka[kc], qf[1][kc], s01);
        }
        __builtin_amdgcn_s_setprio(0);
        if (t + 1 < NT2) LOADK(ka, g * 64 + 2 * (t + 1));      // prefetch

        // QK sub1
        f32x4 s10 = { 0.f, 0.f, 0.f, 0.f }, s11 = { 0.f, 0.f, 0.f, 0.f };
        __builtin_amdgcn_s_setprio(1);
#pragma unroll
        for (int kc = 0; kc < 8; ++kc) {
            s10 = MFMA16(kb2[kc], qf[0][kc], s10);
            s11 = MFMA16(kb2[kc], qf[1][kc], s11);
        }
        __builtin_amdgcn_s_setprio(0);
        if (t + 1 < NT2) LOADK(kb2, g * 64 + 2 * (t + 1) + 1); // prefetch

        // masks
        if (mc0.x == 0) { s00[0] = -1e30f; s01[0] = -1e30f; }
        if (mc0.y == 0) { s00[1] = -1e30f; s01[1] = -1e30f; }
        if (mc0.z == 0) { s00[2] = -1e30f; s01[2] = -1e30f; }
        if (mc0.w == 0) { s00[3] = -1e30f; s01[3] = -1e30f; }
        if (mc1.x == 0) { s10[0] = -1e30f; s11[0] = -1e30f; }
        if (mc1.y == 0) { s10[1] = -1e30f; s11[1] = -1e30f; }
        if (mc1.z == 0) { s10[2] = -1e30f; s11[2] = -1e30f; }
        if (mc1.w == 0) { s10[3] = -1e30f; s11[3] = -1e30f; }
        if (t + 1 < NT2) {
            mc0 = *reinterpret_cast<const int4*>(maskb + g * 1024 + (t + 1) * 32 + l4 * 4);
            mc1 = *reinterpret_cast<const int4*>(maskb + g * 1024 + (t + 1) * 32 + 16 + l4 * 4);
        }

        // ---- softmax over 32 keys (base-2), once per super-tile ----
        float t0 = fmaxf(fmaxf(fmaxf(s00[0], s00[1]), fmaxf(s00[2], s00[3])),
                         fmaxf(fmaxf(s10[0], s10[1]), fmaxf(s10[2], s10[3])));
        float t1 = fmaxf(fmaxf(fmaxf(s01[0], s01[1]), fmaxf(s01[2], s01[3])),
                         fmaxf(fmaxf(s11[0], s11[1]), fmaxf(s11[2], s11[3])));
        t0 = fmaxf(t0, __shfl_xor(t0, 16, 64)); t0 = fmaxf(t0, __shfl_xor(t0, 32, 64));
        t1 = fmaxf(t1, __shfl_xor(t1, 16, 64)); t1 = fmaxf(t1, __shfl_xor(t1, 32, 64));

        if (__any(t0 > m0r + 11.54f || t1 > m1r + 11.54f)) {   // defer-max
            float mn0 = fmaxf(m0r, t0), mn1 = fmaxf(m1r, t1);
            float c0 = exp2f(m0r - mn0), c1 = exp2f(m1r - mn1);
            m0r = mn0; m1r = mn1; l0r *= c0; l1r *= c1;
            float cs = (lane & 16) ? c1 : c0;                  // o cols: q = l31
#pragma unroll
            for (int dt = 0; dt < 8; ++dt) o[dt] *= cs;
        }

        float rs0 = 0.f, rs1 = 0.f;
#pragma unroll
        for (int r = 0; r < 4; ++r) {
            float p;
            p = exp2f(s00[r] - m0r); s00[r] = p; rs0 += p;
            p = exp2f(s10[r] - m0r); s10[r] = p; rs0 += p;
            p = exp2f(s01[r] - m1r); s01[r] = p; rs1 += p;
            p = exp2f(s11[r] - m1r); s11[r] = p; rs1 += p;
        }
        rs0 += __shfl_xor(rs0, 16, 64); rs0 += __shfl_xor(rs0, 32, 64);
        rs1 += __shfl_xor(rs1, 16, 64); rs1 += __shfl_xor(rs1, 32, 64);
        l0r += rs0; l1r += rs1;

        // P -> pw[q][key] f16 (32 keys); reread as PV B-frags
        {
            f16x4 h;
            h = (f16x4){ (_Float16)s00[0], (_Float16)s00[1], (_Float16)s00[2], (_Float16)s00[3] };
            *reinterpret_cast<f16x4*>(pw + l15 * 40 + l4 * 4) = h;
            h = (f16x4){ (_Float16)s10[0], (_Float16)s10[1], (_Float16)s10[2], (_Float16)s10[3] };
            *reinterpret_cast<f16x4*>(pw + l15 * 40 + 16 + l4 * 4) = h;
            h = (f16x4){ (_Float16)s01[0], (_Float16)s01[1], (_Float16)s01[2], (_Float16)s01[3] };
            *reinterpret_cast<f16x4*>(pw + (16 + l15) * 40 + l4 * 4) = h;
            h = (f16x4){ (_Float16)s11[0], (_Float16)s11[1], (_Float16)s11[2], (_Float16)s11[3] };
            *reinterpret_cast<f16x4*>(pw + (16 + l15) * 40 + 16 + l4 * 4) = h;
        }
        f16x8 pf0 = *reinterpret_cast<const f16x8*>(pw + l31 * 40 + l5 * 8);
        f16x8 pf1 = *reinterpret_cast<const f16x8*>(pw + l31 * 40 + 16 + l5 * 8);

        // PV: O^T += V^T P^T over both 16-key sub-tiles
        const char* vb_ = smraw + g * 32768 + (t & 1) * 16384;
        __builtin_amdgcn_s_setprio(1);
#pragma unroll
        for (int dt = 0; dt < 8; ++dt) {
            f16x8 vf0 = *reinterpret_cast<const f16x8*>(vb_ + dt * 1024 + l5 * 512 + l31 * 16);
            o[dt] = MFMA32(vf0, pf0, o[dt]);
            f16x8 vf1 = *reinterpret_cast<const f16x8*>(vb_ + 8192 + dt * 1024 + l5 * 512 + l31 * 16);
            o[dt] = MFMA32(vf1, pf1, o[dt]);
        }
        __builtin_amdgcn_s_setprio(0);
    }
    __syncthreads();   // all warps done with V LDS; safe to reuse as oex

    // ---- epilogue: 4-group split-K merge, two qw passes (base-2) ----
    if (l4 == 0) {
        mex32[(qw * 4 + g) * 32 + l15]      = m0r;
        mex32[(qw * 4 + g) * 32 + 16 + l15] = m1r;
        lex32[(qw * 4 + g) * 32 + l15]      = l0r;
        lex32[(qw * 4 + g) * 32 + 16 + l15] = l1r;
    }
    __syncthreads();

    float mq = (lane & 16) ? m1r : m0r;
    float mst = -1e30f;
#pragma unroll
    for (int g2 = 0; g2 < 4; ++g2)
        mst = fmaxf(mst, mex32[(qw * 4 + g2) * 32 + l31]);
    float osc = exp2f(mq - mst);

#pragma unroll 1
    for (int s = 0; s < 2; ++s) {
        if (qw == s) {
            float* og = oexf + g * (32 * 258);
#pragma unroll
            for (int dt = 0; dt < 8; ++dt)
#pragma unroll
                for (int r = 0; r < 16; ++r) {
                    int d = dt * 32 + (r & 3) + 8 * (r >> 2) + 4 * l5;
                    og[l31 * 258 + d] = o[dt][r] * osc;
                }
        }
        __syncthreads();
        {
            const int q = tid >> 4, dg = tid & 15;
            float mA = mex32[(s * 4 + 0) * 32 + q], mB = mex32[(s * 4 + 1) * 32 + q];
            float mC = mex32[(s * 4 + 2) * 32 + q], mD = mex32[(s * 4 + 3) * 32 + q];
            float ms = fmaxf(fmaxf(mA, mB), fmaxf(mC, mD));
            float lt = lex32[(s * 4 + 0) * 32 + q] * exp2f(mA - ms)
                     + lex32[(s * 4 + 1) * 32 + q] * exp2f(mB - ms)
                     + lex32[(s * 4 + 2) * 32 + q] * exp2f(mC - ms)
                     + lex32[(s * 4 + 3) * 32 + q] * exp2f(mD - ms);
            float inv = 1.f / lt;
#pragma unroll
            for (int i = 0; i < 4; ++i) {
                int d0 = dg * 16 + i * 4;
                f32x4 a = *reinterpret_cast<const f32x4*>(oexf + q * 258 + d0);
#pragma unroll
                for (int g2 = 1; g2 < 4; ++g2) {
                    f32x4 tt = *reinterpret_cast<const f32x4*>(
                        oexf + g2 * (32 * 258) + q * 258 + d0);
                    a[0] += tt[0]; a[1] += tt[1]; a[2] += tt[2]; a[3] += tt[3];
                }
                a[0] *= inv; a[1] *= inv; a[2] *= inv; a[3] *= inv;
                *reinterpret_cast<f32x4*>(
                    outp + base + (size_t)(q0 + s * 32 + q) * Cc + d0) = a;
            }
        }
        __syncthreads();
    }
}

extern "C" void kernel_launch(void* const* d_in, const int* in_sizes, int n_in,
                              void* d_out, int out_size, void* d_ws, size_t ws_size,
                              hipStream_t stream)
{
    (void)in_sizes; (void)n_in; (void)out_size; (void)ws_size;
    const float* x   = (const float*)d_in[0];
    const int*  mask = (const int*)d_in[1];
    const float* Wk  = (const float*)d_in[2];
    const float* Wq  = (const float*)d_in[3];
    const float* Wv  = (const float*)d_in[4];
    float* out = (float*)d_out;

    _Float16* q  = (_Float16*)d_ws;
    _Float16* k  = q + (size_t)BT * Cc;
    _Float16* vt = k + (size_t)BT * Cc;

    dim3 gA(128, 6), blkA(256);
    size_t ldsA = (size_t)(128 + 128) * 264 * sizeof(_Float16);
    qkv_proj<<<gA, blkA, ldsA, stream>>>(x, Wq, Wk, Wv, q, k, vt);

    dim3 gB(256), blkB(512);
    size_t ldsB = 153600;
    attn_kernel<<<gB, blkB, ldsB, stream>>>(q, k, vt, mask, out);
}

// Round 12
// 128.466 us; speedup vs baseline: 2.7553x; 2.7553x over previous
//
#include <hip/hip_runtime.h>

// Round 12: full-register-budget flash attention. Block = 256 thr = 4 waves =
// 1 wave/SIMD -> 512-reg budget/wave (no 256 cap). K,V loaded L2->registers as
// MFMA fragments (R8 tiled layouts), ping-pong prefetch, ZERO main-loop barriers.
// 2 qw(32q) x 2 g(2048 keys) per block; grid 256; 2-way split-K epilogue merge.
//   d_in: 0=x f32, 1=mask i32, 2=Wk, 3=Wq, 4=Wv
// ws (f16): qT [BT/32][8192] | kT [BT/16][4096] | vT [BT/16][4096]
//   qT: [(qh*8+kc)*512 + l4*128 + tok*8 + j]  (x1/16 folded)
//   kT: [kc*512 + ch*128 + key*8 + j]   <-> K[16t+key][kc*32+ch*8+j]
//   vT: [dt*512 + kh*256 + d31*8 + j]   <-> V^T[dt*32+d31][16t+kh*8+j]

typedef __attribute__((ext_vector_type(8)))  _Float16 f16x8;
typedef __attribute__((ext_vector_type(4)))  _Float16 f16x4;
typedef __attribute__((ext_vector_type(4)))  float    f32x4;
typedef __attribute__((ext_vector_type(16))) float    f32x16;

constexpr int Bb = 4;
constexpr int Tt = 4096;
constexpr int Cc = 256;
constexpr int BT = Bb * Tt;

#define MFMA16(a, b, c) __builtin_amdgcn_mfma_f32_16x16x32_f16((a), (b), (c), 0, 0, 0)
#define MFMA32(a, b, c) __builtin_amdgcn_mfma_f32_32x32x16_f16((a), (b), (c), 0, 0, 0)

// ---------------- Kernel A: fused QKV projection (verbatim round 8) ----------
__global__ __launch_bounds__(256) void qkv_proj(
    const float* __restrict__ x,
    const float* __restrict__ Wq, const float* __restrict__ Wk,
    const float* __restrict__ Wv,
    _Float16* __restrict__ qo, _Float16* __restrict__ ko,
    _Float16* __restrict__ vto)
{
    extern __shared__ _Float16 sm[];
    _Float16* xs = sm;              // [128][264]
    _Float16* wsm = sm + 128 * 264; // [128][264]

    const int tid = threadIdx.x;
    const int m0  = blockIdx.x * 128;
    const int ny  = blockIdx.y;
    const int mat = ny >> 1;              // 0=q 1=k 2=v
    const int d0  = (ny & 1) * 128;
    const float* W = (mat == 0) ? Wq : (mat == 1 ? Wk : Wv);

#pragma unroll
    for (int i = 0; i < 32; ++i) {
        int flat = i * 256 + tid;
        int r = flat >> 6, c4 = (flat & 63) << 2;
        float4 v = *reinterpret_cast<const float4*>(x + (size_t)(m0 + r) * Cc + c4);
        f16x4 h = { (_Float16)v.x, (_Float16)v.y, (_Float16)v.z, (_Float16)v.w };
        *reinterpret_cast<f16x4*>(xs + r * 264 + c4) = h;
    }
#pragma unroll
    for (int i = 0; i < 32; ++i) {
        int flat = i * 256 + tid;
        int r = flat >> 6, c4 = (flat & 63) << 2;
        float4 v = *reinterpret_cast<const float4*>(W + (size_t)(d0 + r) * Cc + c4);
        f16x4 h = { (_Float16)v.x, (_Float16)v.y, (_Float16)v.z, (_Float16)v.w };
        *reinterpret_cast<f16x4*>(wsm + r * 264 + c4) = h;
    }
    __syncthreads();

    const int w = tid >> 6, lane = tid & 63;
    const int lr = lane & 15, lg = lane >> 4;

    f32x4 acc[2][8] = {};

#pragma unroll
    for (int kc = 0; kc < 8; ++kc) {
        const int c0 = kc * 32 + lg * 8;
        f16x8 xf[2], wf[8];
#pragma unroll
        for (int mb = 0; mb < 2; ++mb)
            xf[mb] = *reinterpret_cast<const f16x8*>(xs + (w * 32 + mb * 16 + lr) * 264 + c0);
#pragma unroll
        for (int db = 0; db < 8; ++db)
            wf[db] = *reinterpret_cast<const f16x8*>(wsm + (db * 16 + lr) * 264 + c0);
        if (mat != 2) {
#pragma unroll
            for (int mb = 0; mb < 2; ++mb)
#pragma unroll
                for (int db = 0; db < 8; ++db)
                    acc[mb][db] = MFMA16(wf[db], xf[mb], acc[mb][db]);   // D[d][tok]
        } else {
#pragma unroll
            for (int mb = 0; mb < 2; ++mb)
#pragma unroll
                for (int db = 0; db < 8; ++db)
                    acc[mb][db] = MFMA16(xf[mb], wf[db], acc[mb][db]);   // D[tok][d]
        }
    }

    if (mat != 2) {
        const float sc = (mat == 0) ? 0.0625f : 1.0f;
        const int jj  = (lg & 1) * 4;
#pragma unroll
        for (int mb = 0; mb < 2; ++mb)
#pragma unroll
            for (int db = 0; db < 8; ++db) {
                int m  = m0 + w * 32 + mb * 16 + lr;
                int c  = d0 + db * 16 + lg * 4;
                int kc = c >> 5;
                int ch = (c >> 3) & 3;
                f32x4 a = acc[mb][db];
                f16x4 h = { (_Float16)(a.x * sc), (_Float16)(a.y * sc),
                            (_Float16)(a.z * sc), (_Float16)(a.w * sc) };
                if (mat == 0) {
                    size_t off = (size_t)(m >> 5) * 8192 + (((m >> 4) & 1) * 8 + kc) * 512
                               + ch * 128 + (m & 15) * 8 + jj;
                    *reinterpret_cast<f16x4*>(qo + off) = h;
                } else {
                    size_t off = (size_t)(m >> 4) * 4096 + kc * 512
                               + ch * 128 + (m & 15) * 8 + jj;
                    *reinterpret_cast<f16x4*>(ko + off) = h;
                }
            }
    } else {
        const int jj = (lg & 1) * 4;
        const int kh = (lg >> 1) & 1;
#pragma unroll
        for (int mb = 0; mb < 2; ++mb)
#pragma unroll
            for (int db = 0; db < 8; ++db) {
                int d = d0 + db * 16 + lr;
                int m = m0 + w * 32 + mb * 16 + lg * 4;
                f32x4 a = acc[mb][db];
                f16x4 h = { (_Float16)a.x, (_Float16)a.y, (_Float16)a.z, (_Float16)a.w };
                size_t off = (size_t)(m >> 4) * 4096 + (d >> 5) * 512
                           + kh * 256 + (d & 31) * 8 + jj;
                *reinterpret_cast<f16x4*>(vto + off) = h;
            }
    }
}

// ---------------- Kernel B: register-resident flash attention ----------------
// LDS (bytes): [0,6144) per-warp P [4][32][24] f16 | [6144,6656) mex f32[4][32]
//              [6656,7168) lex | [8192,74240) oex f32[2 qw][32 q][258]
__global__ __launch_bounds__(256, 1) void attn_kernel(
    const _Float16* __restrict__ qb, const _Float16* __restrict__ kb,
    const _Float16* __restrict__ vtb, const int* __restrict__ mask,
    float* __restrict__ outp)
{
    extern __shared__ char smraw[];
    float* mex  = (float*)(smraw + 6144);
    float* lex  = (float*)(smraw + 6656);
    float* oexf = (float*)(smraw + 8192);

    const int tid = threadIdx.x, w = tid >> 6, lane = tid & 63;
    const int qw = w >> 1, g = w & 1;
    const int l15 = lane & 15, l4 = lane >> 4;
    const int l31 = lane & 31, l5 = lane >> 5;

    const int bid = blockIdx.x;
    const int b   = (bid & 7) >> 1;                    // batch -> XCD pair
    const int qt  = ((bid >> 3) << 1) | (bid & 1);     // [0,64)
    const int q0  = qt * 64;
    const size_t base = (size_t)b * Tt * Cc;
    const int* maskb = mask + (size_t)b * Tt;
    const _Float16* kTb = kb + base;
    const _Float16* vTb = vtb + base;

    // Q fragments: Q[q0 + qw*32 + qh*16 + l15][kc*32 + l4*8 + j]  (x1/16)
    f16x8 qf[2][8];
    {
        const _Float16* qTb = qb + (size_t)(b * 128 + qt * 2 + qw) * 8192;
#pragma unroll
        for (int qh = 0; qh < 2; ++qh)
#pragma unroll
            for (int kc = 0; kc < 8; ++kc)
                qf[qh][kc] = *reinterpret_cast<const f16x8*>(
                    qTb + (qh * 8 + kc) * 512 + l4 * 128 + l15 * 8);
    }

    _Float16* pw = (_Float16*)smraw + w * 768;         // [32][24] private bounce

    f32x16 o[8] = {};                  // O^T[d = dt*32+(r&3)+8*(r>>2)+4*l5][q=l31]
    float m0r = -60.f, m1r = -60.f, l0r = 0.f, l1r = 0.f;

    // K/V/mask tile -> registers (all L2-resident; R8 tiled layouts)
    auto LOADT = [&](f16x8 (&kr)[8], f16x8 (&vr)[8], int4& mc, int tile) {
        const _Float16* kp = kTb + (size_t)tile * 4096 + l4 * 128 + l15 * 8;
#pragma unroll
        for (int kc = 0; kc < 8; ++kc)
            kr[kc] = *reinterpret_cast<const f16x8*>(kp + kc * 512);
        const _Float16* vp = vTb + (size_t)tile * 4096 + l5 * 256 + l31 * 8;
#pragma unroll
        for (int dt = 0; dt < 8; ++dt)
            vr[dt] = *reinterpret_cast<const f16x8*>(vp + dt * 512);
        mc = *reinterpret_cast<const int4*>(maskb + tile * 16 + l4 * 4);
    };

    auto COMPUTE = [&](f16x8 (&kr)[8], f16x8 (&vr)[8], int4 mc) {
        // QK: S^T[key = l4*4 + r][q = qh*16 + l15]
        f32x4 s40 = { 0.f, 0.f, 0.f, 0.f }, s41 = { 0.f, 0.f, 0.f, 0.f };
#pragma unroll
        for (int kc = 0; kc < 8; ++kc) {
            s40 = MFMA16(kr[kc], qf[0][kc], s40);
            s41 = MFMA16(kr[kc], qf[1][kc], s41);
        }
        if (mc.x == 0) { s40[0] = -1e30f; s41[0] = -1e30f; }
        if (mc.y == 0) { s40[1] = -1e30f; s41[1] = -1e30f; }
        if (mc.z == 0) { s40[2] = -1e30f; s41[2] = -1e30f; }
        if (mc.w == 0) { s40[3] = -1e30f; s41[3] = -1e30f; }

        // online softmax per qh (q = l15; keys across l4 groups)
        float t0 = fmaxf(fmaxf(s40[0], s40[1]), fmaxf(s40[2], s40[3]));
        float t1 = fmaxf(fmaxf(s41[0], s41[1]), fmaxf(s41[2], s41[3]));
        t0 = fmaxf(t0, __shfl_xor(t0, 16, 64)); t0 = fmaxf(t0, __shfl_xor(t0, 32, 64));
        t1 = fmaxf(t1, __shfl_xor(t1, 16, 64)); t1 = fmaxf(t1, __shfl_xor(t1, 32, 64));

        if (__any(t0 > m0r + 8.f || t1 > m1r + 8.f)) {     // defer-max
            float mn0 = fmaxf(m0r, t0), mn1 = fmaxf(m1r, t1);
            float c0 = __expf(m0r - mn0), c1 = __expf(m1r - mn1);
            m0r = mn0; m1r = mn1; l0r *= c0; l1r *= c1;
            float cs = (lane & 16) ? c1 : c0;              // o cols: q = l31
#pragma unroll
            for (int dt = 0; dt < 8; ++dt) o[dt] *= cs;
        }

        float rs0 = 0.f, rs1 = 0.f;
#pragma unroll
        for (int r = 0; r < 4; ++r) {
            float p0 = __expf(s40[r] - m0r); s40[r] = p0; rs0 += p0;
            float p1 = __expf(s41[r] - m1r); s41[r] = p1; rs1 += p1;
        }
        rs0 += __shfl_xor(rs0, 16, 64); rs0 += __shfl_xor(rs0, 32, 64);
        rs1 += __shfl_xor(rs1, 16, 64); rs1 += __shfl_xor(rs1, 32, 64);
        l0r += rs0; l1r += rs1;

        // P -> pw[q][k] f16; reread as PV B-frag (private, in-wave lgkm-ordered)
        {
            f16x4 h0 = { (_Float16)s40[0], (_Float16)s40[1], (_Float16)s40[2], (_Float16)s40[3] };
            f16x4 h1 = { (_Float16)s41[0], (_Float16)s41[1], (_Float16)s41[2], (_Float16)s41[3] };
            *reinterpret_cast<f16x4*>(pw + l15 * 24 + l4 * 4)        = h0;
            *reinterpret_cast<f16x4*>(pw + (16 + l15) * 24 + l4 * 4) = h1;
        }
        f16x8 pf = *reinterpret_cast<const f16x8*>(pw + l31 * 24 + l5 * 8);

        // PV: O^T += V^T P^T  (V frags straight from registers)
#pragma unroll
        for (int dt = 0; dt < 8; ++dt)
            o[dt] = MFMA32(vr[dt], pf, o[dt]);
    };

    // main loop: 128 tiles of 16 keys, register ping-pong, NO barriers
    f16x8 kA[8], vA[8], kB[8], vB[8];
    int4 mA_, mB_;
    const int ktb = g * 128;                 // this warp's tiles [ktb, ktb+128)
    LOADT(kA, vA, mA_, ktb);
#pragma unroll 1
    for (int t2 = 0; t2 < 64; ++t2) {
        LOADT(kB, vB, mB_, ktb + 2 * t2 + 1);
        COMPUTE(kA, vA, mA_);
        LOADT(kA, vA, mA_, (2 * t2 + 2 < 128) ? (ktb + 2 * t2 + 2) : ktb);  // last: dummy
        COMPUTE(kB, vB, mB_);
    }

    // ---- epilogue: 2-way split-K merge ----
    __syncthreads();
    if (l4 == 0) {
        mex[w * 32 + l15]      = m0r;  mex[w * 32 + 16 + l15] = m1r;
        lex[w * 32 + l15]      = l0r;  lex[w * 32 + 16 + l15] = l1r;
    }
    __syncthreads();

    {
        float mq  = (lane & 16) ? m1r : m0r;
        float mA2 = mex[(qw * 2 + 0) * 32 + l31];
        float mB2 = mex[(qw * 2 + 1) * 32 + l31];
        float mst = fmaxf(mA2, mB2);
        float osc = __expf(mq - mst);
        float* oq = oexf + qw * (32 * 258);
        if (g == 1) {
#pragma unroll
            for (int dt = 0; dt < 8; ++dt)
#pragma unroll
                for (int r = 0; r < 16; ++r) {
                    int d = dt * 32 + (r & 3) + 8 * (r >> 2) + 4 * l5;
                    oq[l31 * 258 + d] = o[dt][r] * osc;
                }
        }
        __syncthreads();
        if (g == 0) {
#pragma unroll
            for (int dt = 0; dt < 8; ++dt)
#pragma unroll
                for (int r = 0; r < 16; ++r) {
                    int d = dt * 32 + (r & 3) + 8 * (r >> 2) + 4 * l5;
                    oq[l31 * 258 + d] += o[dt][r] * osc;
                }
        }
        __syncthreads();
    }

    // readout: 256 threads -> q = tid>>2 in [0,64), dseg = (tid&3)*64
    {
        const int q = tid >> 2, ds0 = (tid & 3) * 64;
        const int qws = q >> 5, ql = q & 31;
        float mA2 = mex[(qws * 2 + 0) * 32 + ql];
        float mB2 = mex[(qws * 2 + 1) * 32 + ql];
        float ms  = fmaxf(mA2, mB2);
        float lt  = lex[(qws * 2 + 0) * 32 + ql] * __expf(mA2 - ms)
                  + lex[(qws * 2 + 1) * 32 + ql] * __expf(mB2 - ms);
        float inv = 1.f / lt;
        const float* src = oexf + qws * (32 * 258) + ql * 258 + ds0;
        float* dst = outp + base + (size_t)(q0 + q) * Cc + ds0;
#pragma unroll
        for (int i = 0; i < 16; ++i) {
            f32x4 a = *reinterpret_cast<const f32x4*>(src + 4 * i);
            a[0] *= inv; a[1] *= inv; a[2] *= inv; a[3] *= inv;
            *reinterpret_cast<f32x4*>(dst + 4 * i) = a;
        }
    }
}

extern "C" void kernel_launch(void* const* d_in, const int* in_sizes, int n_in,
                              void* d_out, int out_size, void* d_ws, size_t ws_size,
                              hipStream_t stream)
{
    (void)in_sizes; (void)n_in; (void)out_size; (void)ws_size;
    const float* x   = (const float*)d_in[0];
    const int*  mask = (const int*)d_in[1];
    const float* Wk  = (const float*)d_in[2];
    const float* Wq  = (const float*)d_in[3];
    const float* Wv  = (const float*)d_in[4];
    float* out = (float*)d_out;

    _Float16* q  = (_Float16*)d_ws;
    _Float16* k  = q + (size_t)BT * Cc;
    _Float16* vt = k + (size_t)BT * Cc;

    dim3 gA(128, 6), blkA(256);
    size_t ldsA = (size_t)(128 + 128) * 264 * sizeof(_Float16);
    qkv_proj<<<gA, blkA, ldsA, stream>>>(x, Wq, Wk, Wv, q, k, vt);

    dim3 gB(256), blkB(256);
    size_t ldsB = 74240;
    attn_kernel<<<gB, blkB, ldsB, stream>>>(q, k, vt, mask, out);
}